// Round 2
// baseline (1416.538 us; speedup 1.0000x reference)
//
#include <hip/hip_runtime.h>
#include <hip/hip_bf16.h>

// GCN_5016521802361: 2x SAGEConv(aggr='lstm', project=True), N=50000, D=16, F=128, C=40.
// Round 2: dtype-self-detecting (inputs may be f32 or bf16; probe decides on-device).
// Pipeline per layer:
//   xp   = relu(x @ Wp^T + bp)                      [N,128]
//   Y    = xp @ Wih^T + bih + bhh                   [N,512]   (Wih hoisted out of recurrence)
//   aggr = LSTM_over_neighbors(Y[edge_src], Whh)    [N,128]   (MFMA recurrence, Whh in VGPRs)
//   out  = [relu](aggr @ Wl^T + bl + xin @ Wr^T)

typedef __hip_bfloat16 bf16;
typedef __attribute__((ext_vector_type(8))) short short8;
typedef __attribute__((ext_vector_type(4))) float floatx4;

__device__ __forceinline__ float bf2f(bf16 v) { return __bfloat162float(v); }
__device__ __forceinline__ bf16  f2bf(float v) { return __float2bfloat16(v); }
__device__ __forceinline__ float sigm(float x)  { return 1.f / (1.f + __expf(-x)); }
__device__ __forceinline__ float tanh_(float x) { return 1.f - 2.f / (__expf(2.f * x) + 1.f); }

__global__ void detect_dtype(const unsigned short* __restrict__ xb, int* __restrict__ flag) {
    int cnt = 0;
    for (int i = threadIdx.x; i < 1024; i += 64) {
        int e = (xb[i] >> 7) & 0xFF;
        cnt += (e >= 0xC8);   // impossible exponent for N(0,1) bf16 data
    }
#pragma unroll
    for (int off = 32; off; off >>= 1) cnt += __shfl_down(cnt, off);
    if (threadIdx.x == 0) *flag = (cnt >= 16) ? 1 : 0;   // 1 => inputs are float32
}

struct Cvt { const void* src; bf16* dst; int n; };
struct CvtAll { Cvt t[19]; };

__global__ void convert_inputs(CvtAll ca, const int* __restrict__ flag) {
    const bool isf32 = (*flag != 0);
    const int stride = gridDim.x * blockDim.x;
    const int tid0 = blockIdx.x * blockDim.x + threadIdx.x;
#pragma unroll 1
    for (int k = 0; k < 19; k++) {
        const int n = ca.t[k].n;
        const float* sf = (const float*)ca.t[k].src;
        const bf16*  sb = (const bf16*)ca.t[k].src;
        bf16* d = ca.t[k].dst;
        for (int i = tid0; i < n; i += stride)
            d[i] = isf32 ? f2bf(sf[i]) : sb[i];
    }
}

template <int NCT, bool RELU, bool BIAS2, bool DUAL, bool OUTF>
__global__ __launch_bounds__(256, 1) void gemm_bias(
    const bf16* __restrict__ A, const bf16* __restrict__ B,
    const bf16* __restrict__ bias, const bf16* __restrict__ bias2,
    const bf16* __restrict__ A2, const bf16* __restrict__ B2,
    void* __restrict__ Cv, const int* __restrict__ oflag,
    int N, int nbt, int ldc)
{
    const int tid = threadIdx.x;
    const int w = tid >> 6, l = tid & 63, q = l >> 4, lid = l & 15;
    const int rowbase = blockIdx.x * 64 + w * 16;
    const int colslice = blockIdx.y * 128;

    int arow = rowbase + lid;
    if (arow >= N) arow = N - 1;

    floatx4 acc[NCT];
#pragma unroll
    for (int ct = 0; ct < NCT; ct++) acc[ct] = (floatx4)(0.f);

    short8 bfrag[NCT][4];
#pragma unroll
    for (int ct = 0; ct < NCT; ct++) {
        int j = colslice + ct * 16 + lid;
        if (j >= nbt) j = nbt - 1;
#pragma unroll
        for (int kt = 0; kt < 4; kt++)
            bfrag[ct][kt] = *(const short8*)(B + (size_t)j * 128 + kt * 32 + q * 8);
    }
#pragma unroll
    for (int kt = 0; kt < 4; kt++) {
        short8 af = *(const short8*)(A + (size_t)arow * 128 + kt * 32 + q * 8);
#pragma unroll
        for (int ct = 0; ct < NCT; ct++)
            acc[ct] = __builtin_amdgcn_mfma_f32_16x16x32_bf16(af, bfrag[ct][kt], acc[ct], 0, 0, 0);
    }
    if constexpr (DUAL) {
#pragma unroll
        for (int ct = 0; ct < NCT; ct++) {
            int j = colslice + ct * 16 + lid;
            if (j >= nbt) j = nbt - 1;
#pragma unroll
            for (int kt = 0; kt < 4; kt++)
                bfrag[ct][kt] = *(const short8*)(B2 + (size_t)j * 128 + kt * 32 + q * 8);
        }
#pragma unroll
        for (int kt = 0; kt < 4; kt++) {
            short8 af = *(const short8*)(A2 + (size_t)arow * 128 + kt * 32 + q * 8);
#pragma unroll
            for (int ct = 0; ct < NCT; ct++)
                acc[ct] = __builtin_amdgcn_mfma_f32_16x16x32_bf16(af, bfrag[ct][kt], acc[ct], 0, 0, 0);
        }
    }
    bool of32 = false;
    if constexpr (OUTF) of32 = (*oflag != 0);
#pragma unroll
    for (int ct = 0; ct < NCT; ct++) {
        int cg = colslice + ct * 16 + lid;
        int cb = cg < nbt ? cg : nbt - 1;
        float bv = bf2f(bias[cb]);
        if constexpr (BIAS2) bv += bf2f(bias2[cb]);
#pragma unroll
        for (int r = 0; r < 4; r++) {
            int row = rowbase + q * 4 + r;
            float v = acc[ct][r] + bv;
            if constexpr (RELU) v = fmaxf(v, 0.f);
            if (row < N && cg < nbt) {
                size_t idx = (size_t)row * ldc + cg;
                if constexpr (OUTF) {
                    if (of32) ((float*)Cv)[idx] = v;
                    else      ((bf16*)Cv)[idx] = f2bf(v);
                } else {
                    ((bf16*)Cv)[idx] = f2bf(v);
                }
            }
        }
    }
}

__global__ __launch_bounds__(256, 1) void lstm_aggr(
    const bf16* __restrict__ Y, const int* __restrict__ esrc,
    const bf16* __restrict__ Whh, bf16* __restrict__ aggr, int N)
{
    __shared__ alignas(16) bf16 hbuf[2][32][136];
    __shared__ int srcl[32][16];

    const int tid = threadIdx.x;
    const int w = tid >> 6, l = tid & 63, q = l >> 4, lid = l & 15;
    const int nodebase = blockIdx.x * 32;

    for (int i = tid; i < 32 * 16; i += 256) {
        int node = nodebase + (i >> 4);
        if (node >= N) node = N - 1;
        srcl[i >> 4][i & 15] = esrc[(size_t)node * 16 + (i & 15)];
    }
    for (int i = tid; i < 32 * 136; i += 256) ((short*)hbuf[0])[i] = 0;

    short8 bfr[4][2][4];
#pragma unroll
    for (int g = 0; g < 4; g++)
#pragma unroll
        for (int u = 0; u < 2; u++) {
            int n = g * 128 + w * 32 + u * 16 + lid;
#pragma unroll
            for (int kt = 0; kt < 4; kt++)
                bfr[g][u][kt] = *(const short8*)(Whh + (size_t)n * 128 + kt * 32 + q * 8);
        }

    float c[2][2][4];
#pragma unroll
    for (int rt = 0; rt < 2; rt++)
#pragma unroll
        for (int u = 0; u < 2; u++)
#pragma unroll
            for (int r = 0; r < 4; r++) c[rt][u][r] = 0.f;

    __syncthreads();

    for (int t = 0; t < 16; t++) {
        const int cur = t & 1, nxt = cur ^ 1;
        floatx4 acc[2][4][2];

#pragma unroll
        for (int rt = 0; rt < 2; rt++)
#pragma unroll
            for (int r = 0; r < 4; r++) {
                int nl = rt * 16 + q * 4 + r;
                int s = srcl[nl][t];
                const bf16* yb = Y + (size_t)s * 512 + w * 32 + lid;
#pragma unroll
                for (int g = 0; g < 4; g++)
#pragma unroll
                    for (int u = 0; u < 2; u++)
                        acc[rt][g][u][r] = bf2f(yb[g * 128 + u * 16]);
            }

#pragma unroll
        for (int kt = 0; kt < 4; kt++) {
            short8 af0 = *(const short8*)&hbuf[cur][lid][kt * 32 + q * 8];
            short8 af1 = *(const short8*)&hbuf[cur][16 + lid][kt * 32 + q * 8];
#pragma unroll
            for (int g = 0; g < 4; g++)
#pragma unroll
                for (int u = 0; u < 2; u++) {
                    acc[0][g][u] = __builtin_amdgcn_mfma_f32_16x16x32_bf16(af0, bfr[g][u][kt], acc[0][g][u], 0, 0, 0);
                    acc[1][g][u] = __builtin_amdgcn_mfma_f32_16x16x32_bf16(af1, bfr[g][u][kt], acc[1][g][u], 0, 0, 0);
                }
        }

#pragma unroll
        for (int rt = 0; rt < 2; rt++)
#pragma unroll
            for (int u = 0; u < 2; u++)
#pragma unroll
                for (int r = 0; r < 4; r++) {
                    float si = sigm(acc[rt][0][u][r]);
                    float sf = sigm(acc[rt][1][u][r]);
                    float tg = tanh_(acc[rt][2][u][r]);
                    float so = sigm(acc[rt][3][u][r]);
                    float cn = sf * c[rt][u][r] + si * tg;
                    c[rt][u][r] = cn;
                    float hn = so * tanh_(cn);
                    int row = rt * 16 + q * 4 + r;
                    int col = w * 32 + u * 16 + lid;
                    if (t < 15) {
                        hbuf[nxt][row][col] = f2bf(hn);
                    } else {
                        int node = nodebase + row;
                        if (node < N) aggr[(size_t)node * 128 + col] = f2bf(hn);
                    }
                }
        __syncthreads();
    }
}

extern "C" void kernel_launch(void* const* d_in, const int* in_sizes, int n_in,
                              void* d_out, int out_size, void* d_ws, size_t ws_size,
                              hipStream_t stream)
{
    const int N = 50000;
    const int* es = (const int*)d_in[1];
    char* ws = (char*)d_ws;

    // converted bf16 copies of the 19 used float tensors @[0,15MB)
    static const int idxs[19] = {0, 8,9,10,11,12,13,14,15,16, 17,18,19,20,21,22,23,24,25};
    bf16* conv[19];
    size_t off = 0;
    CvtAll ca;
    for (int k = 0; k < 19; k++) {
        conv[k] = (bf16*)ws + off;
        ca.t[k].src = d_in[idxs[k]];
        ca.t[k].dst = conv[k];
        ca.t[k].n = in_sizes[idxs[k]];
        off += (size_t)((in_sizes[idxs[k]] + 63) & ~63);
    }
    int* flag = (int*)(ws + ((size_t)15 << 20));
    bf16* xp   = (bf16*)(ws + ((size_t)16 << 20));   // [N,128], reused as aggr
    bf16* Y    = (bf16*)(ws + ((size_t)30 << 20));   // [N,512]
    bf16* h1   = (bf16*)(ws + ((size_t)84 << 20));   // [N,128]
    bf16* aggr = xp;

    const bf16 *xc  = conv[0];
    const bf16 *Wp1 = conv[1],  *bp1 = conv[2],  *Wih1 = conv[3],  *Whh1 = conv[4];
    const bf16 *bih1 = conv[5], *bhh1 = conv[6], *Wl1 = conv[7],   *bl1 = conv[8],  *Wr1 = conv[9];
    const bf16 *Wp2 = conv[10], *bp2 = conv[11], *Wih2 = conv[12], *Whh2 = conv[13];
    const bf16 *bih2 = conv[14], *bhh2 = conv[15], *Wl2 = conv[16], *bl2 = conv[17], *Wr2 = conv[18];

    dim3 blk(256);
    const int gx = (N + 63) / 64;
    const int gl = (N + 31) / 32;

    detect_dtype<<<dim3(1), dim3(64), 0, stream>>>((const unsigned short*)d_in[0], flag);
    convert_inputs<<<dim3(1024), blk, 0, stream>>>(ca, flag);

    // ---- layer 1 ----
    gemm_bias<8, true, false, false, false><<<dim3(gx, 1), blk, 0, stream>>>(
        xc, Wp1, bp1, nullptr, nullptr, nullptr, xp, nullptr, N, 128, 128);
    gemm_bias<8, false, true, false, false><<<dim3(gx, 4), blk, 0, stream>>>(
        xp, Wih1, bih1, bhh1, nullptr, nullptr, Y, nullptr, N, 512, 512);
    lstm_aggr<<<dim3(gl), blk, 0, stream>>>(Y, es, Whh1, aggr, N);
    gemm_bias<8, true, false, true, false><<<dim3(gx, 1), blk, 0, stream>>>(
        aggr, Wl1, bl1, nullptr, xc, Wr1, h1, nullptr, N, 128, 128);

    // ---- layer 2 ----
    gemm_bias<8, true, false, false, false><<<dim3(gx, 1), blk, 0, stream>>>(
        h1, Wp2, bp2, nullptr, nullptr, nullptr, xp, nullptr, N, 128, 128);
    gemm_bias<8, false, true, false, false><<<dim3(gx, 4), blk, 0, stream>>>(
        xp, Wih2, bih2, bhh2, nullptr, nullptr, Y, nullptr, N, 512, 512);
    lstm_aggr<<<dim3(gl), blk, 0, stream>>>(Y, es, Whh2, aggr, N);
    gemm_bias<3, false, false, true, true><<<dim3(gx, 1), blk, 0, stream>>>(
        aggr, Wl2, bl2, nullptr, h1, Wr2, d_out, flag, N, 40, 40);
}

// Round 3
// 894.373 us; speedup vs baseline: 1.5838x; 1.5838x over previous
//
#include <hip/hip_runtime.h>
#include <hip/hip_bf16.h>

// GCN_5016521802361: 2x SAGEConv(aggr='lstm', project=True), N=50000, D=16, F=128, C=40.
// Round 3: transposed-MFMA LSTM recurrence. G^T = Whh * h^T so that in C-layout each
// lane owns ONE node (col=lane&15) and its Y-gather is 4-consecutive-col chunks ->
// 8x global_load_dwordx2 per thread per step (was 64 scalar ushort), prefetched one
// step ahead. h' writes become ds_write_b64. rcp-based sigmoid/tanh.

typedef __hip_bfloat16 bf16;
typedef __attribute__((ext_vector_type(8))) short short8;
typedef __attribute__((ext_vector_type(4))) short short4v;
typedef __attribute__((ext_vector_type(4))) float floatx4;

__device__ __forceinline__ float bf2f(bf16 v) { return __bfloat162float(v); }
__device__ __forceinline__ bf16  f2bf(float v) { return __float2bfloat16(v); }
__device__ __forceinline__ float bfs2f(short s) {
    union { float f; unsigned u; } v; v.u = ((unsigned)(unsigned short)s) << 16; return v.f;
}
__device__ __forceinline__ short f2bfs(float v) {
    bf16 b = __float2bfloat16(v); return *(short*)&b;
}
// fast activations: v_exp + v_rcp (no exact-division sequence)
__device__ __forceinline__ float sigm(float x)  { return __builtin_amdgcn_rcpf(1.f + __expf(-x)); }
__device__ __forceinline__ float tanh_(float x) { return 1.f - 2.f * __builtin_amdgcn_rcpf(__expf(2.f * x) + 1.f); }

__global__ void detect_dtype(const unsigned short* __restrict__ xb, int* __restrict__ flag) {
    int cnt = 0;
    for (int i = threadIdx.x; i < 1024; i += 64) {
        int e = (xb[i] >> 7) & 0xFF;
        cnt += (e >= 0xC8);   // impossible exponent for N(0,1) bf16 data
    }
#pragma unroll
    for (int off = 32; off; off >>= 1) cnt += __shfl_down(cnt, off);
    if (threadIdx.x == 0) *flag = (cnt >= 16) ? 1 : 0;   // 1 => inputs are float32
}

struct Cvt { const void* src; bf16* dst; int n; };
struct CvtAll { Cvt t[19]; };

__global__ void convert_inputs(CvtAll ca, const int* __restrict__ flag) {
    const bool isf32 = (*flag != 0);
    const int stride = gridDim.x * blockDim.x;
    const int tid0 = blockIdx.x * blockDim.x + threadIdx.x;
#pragma unroll 1
    for (int k = 0; k < 19; k++) {
        const int n = ca.t[k].n;
        const float* sf = (const float*)ca.t[k].src;
        const bf16*  sb = (const bf16*)ca.t[k].src;
        bf16* d = ca.t[k].dst;
        for (int i = tid0; i < n; i += stride)
            d[i] = isf32 ? f2bf(sf[i]) : sb[i];
    }
}

template <int NCT, bool RELU, bool BIAS2, bool DUAL, bool OUTF>
__global__ __launch_bounds__(256, 1) void gemm_bias(
    const bf16* __restrict__ A, const bf16* __restrict__ B,
    const bf16* __restrict__ bias, const bf16* __restrict__ bias2,
    const bf16* __restrict__ A2, const bf16* __restrict__ B2,
    void* __restrict__ Cv, const int* __restrict__ oflag,
    int N, int nbt, int ldc)
{
    const int tid = threadIdx.x;
    const int w = tid >> 6, l = tid & 63, q = l >> 4, lid = l & 15;
    const int rowbase = blockIdx.x * 64 + w * 16;
    const int colslice = blockIdx.y * 128;

    int arow = rowbase + lid;
    if (arow >= N) arow = N - 1;

    floatx4 acc[NCT];
#pragma unroll
    for (int ct = 0; ct < NCT; ct++) acc[ct] = (floatx4)(0.f);

    short8 bfrag[NCT][4];
#pragma unroll
    for (int ct = 0; ct < NCT; ct++) {
        int j = colslice + ct * 16 + lid;
        if (j >= nbt) j = nbt - 1;
#pragma unroll
        for (int kt = 0; kt < 4; kt++)
            bfrag[ct][kt] = *(const short8*)(B + (size_t)j * 128 + kt * 32 + q * 8);
    }
#pragma unroll
    for (int kt = 0; kt < 4; kt++) {
        short8 af = *(const short8*)(A + (size_t)arow * 128 + kt * 32 + q * 8);
#pragma unroll
        for (int ct = 0; ct < NCT; ct++)
            acc[ct] = __builtin_amdgcn_mfma_f32_16x16x32_bf16(af, bfrag[ct][kt], acc[ct], 0, 0, 0);
    }
    if constexpr (DUAL) {
#pragma unroll
        for (int ct = 0; ct < NCT; ct++) {
            int j = colslice + ct * 16 + lid;
            if (j >= nbt) j = nbt - 1;
#pragma unroll
            for (int kt = 0; kt < 4; kt++)
                bfrag[ct][kt] = *(const short8*)(B2 + (size_t)j * 128 + kt * 32 + q * 8);
        }
#pragma unroll
        for (int kt = 0; kt < 4; kt++) {
            short8 af = *(const short8*)(A2 + (size_t)arow * 128 + kt * 32 + q * 8);
#pragma unroll
            for (int ct = 0; ct < NCT; ct++)
                acc[ct] = __builtin_amdgcn_mfma_f32_16x16x32_bf16(af, bfrag[ct][kt], acc[ct], 0, 0, 0);
        }
    }
    bool of32 = false;
    if constexpr (OUTF) of32 = (*oflag != 0);
#pragma unroll
    for (int ct = 0; ct < NCT; ct++) {
        int cg = colslice + ct * 16 + lid;
        int cb = cg < nbt ? cg : nbt - 1;
        float bv = bf2f(bias[cb]);
        if constexpr (BIAS2) bv += bf2f(bias2[cb]);
#pragma unroll
        for (int r = 0; r < 4; r++) {
            int row = rowbase + q * 4 + r;
            float v = acc[ct][r] + bv;
            if constexpr (RELU) v = fmaxf(v, 0.f);
            if (row < N && cg < nbt) {
                size_t idx = (size_t)row * ldc + cg;
                if constexpr (OUTF) {
                    if (of32) ((float*)Cv)[idx] = v;
                    else      ((bf16*)Cv)[idx] = f2bf(v);
                } else {
                    ((bf16*)Cv)[idx] = f2bf(v);
                }
            }
        }
    }
}

// ---------------------------------------------------------------------------
// LSTM neighbor aggregation, TRANSPOSED recurrence: per step compute
// G^T[512 gates][16 nodes] = Whh * h^T.  Block = 16 nodes, 256 thr (4 waves).
// Wave w owns gate-tiles {2w+hl+8g : hl in 0..1, g in 0..3} -> hidden cols
// [32w, 32w+32).  A = Whh rows (VGPR-resident, 128 regs), B = h rows from LDS
// via ds_read_b128.  C-layout: row=gatecol(q*4+r), col=node(lane&15) -> each
// lane serves ONE node; Y gather = 8 x dwordx2 per thread per step, prefetched
// one step ahead.  c-state in 8 regs; h' -> ds_write_b64.
// ---------------------------------------------------------------------------
__global__ __launch_bounds__(256, 2) void lstm_aggr(
    const bf16* __restrict__ Y,     // [N,512] pre-activations incl. both biases
    const int* __restrict__ esrc,   // [N,16]
    const bf16* __restrict__ Whh,   // [512,128]
    bf16* __restrict__ aggr,        // [N,128] out: final h
    int N)
{
    __shared__ alignas(16) bf16 hb[2][16][136];
    __shared__ int srcl[16][16];    // [t][node]

    const int tid = threadIdx.x;
    const int w = tid >> 6, l = tid & 63, q = l >> 4, lid = l & 15;
    const int nodebase = blockIdx.x * 16;   // N = 50000 = 3125*16, exact

    // srcl[t][node] (coalesced read, transposed store)
    {
        int node = tid >> 4, t = tid & 15;
        srcl[t][node] = esrc[(size_t)(nodebase + node) * 16 + t];
    }
    for (int i = tid; i < 16 * 136; i += 256) ((short*)hb[0])[i] = 0;

    // Whh A-fragments: wf[hl][g][kt]; A-row = gatecol = (2w+hl+8g)*16 + lid
    short8 wf[2][4][4];
#pragma unroll
    for (int hl = 0; hl < 2; hl++)
#pragma unroll
        for (int g = 0; g < 4; g++) {
            int gc = (2 * w + hl + 8 * g) * 16 + lid;
#pragma unroll
            for (int kt = 0; kt < 4; kt++)
                wf[hl][g][kt] = *(const short8*)(Whh + (size_t)gc * 128 + kt * 32 + q * 8);
        }

    float c[2][4];   // [hl][r] cell state for node `lid`, hc = 32w+16hl+4q+r
#pragma unroll
    for (int hl = 0; hl < 2; hl++)
#pragma unroll
        for (int r = 0; r < 4; r++) c[hl][r] = 0.f;

    __syncthreads();

    // preload Y for t=0: yv[buf][hl][g] = Y[s][(2w+hl+8g)*16 + q*4 .. +3]
    short4v yv[2][2][4];
    {
        int s0 = srcl[0][lid];
        const bf16* yb = Y + (size_t)s0 * 512 + q * 4;
#pragma unroll
        for (int hl = 0; hl < 2; hl++)
#pragma unroll
            for (int g = 0; g < 4; g++)
                yv[0][hl][g] = *(const short4v*)(yb + (2 * w + hl + 8 * g) * 16);
    }

#pragma unroll 2
    for (int t = 0; t < 16; t++) {
        const int cur = t & 1, nxt = cur ^ 1;

        // acc init from prefetched Y (C-layout: row=gatecol q*4+r, col=node lid)
        floatx4 acc[2][4];
#pragma unroll
        for (int hl = 0; hl < 2; hl++)
#pragma unroll
            for (int g = 0; g < 4; g++)
#pragma unroll
                for (int r = 0; r < 4; r++)
                    acc[hl][g][r] = bfs2f(yv[cur][hl][g][r]);

        // prefetch Y for t+1 (latency hidden under MFMA + gate VALU)
        if (t < 15) {
            int sn = srcl[t + 1][lid];
            const bf16* yb = Y + (size_t)sn * 512 + q * 4;
#pragma unroll
            for (int hl = 0; hl < 2; hl++)
#pragma unroll
                for (int g = 0; g < 4; g++)
                    yv[nxt][hl][g] = *(const short4v*)(yb + (2 * w + hl + 8 * g) * 16);
        }

        // G^T += Whh * h^T : B-frag = h[node=lid][k] via ds_read_b128
#pragma unroll
        for (int kt = 0; kt < 4; kt++) {
            short8 bh = *(const short8*)&hb[cur][lid][kt * 32 + q * 8];
#pragma unroll
            for (int hl = 0; hl < 2; hl++)
#pragma unroll
                for (int g = 0; g < 4; g++)
                    acc[hl][g] = __builtin_amdgcn_mfma_f32_16x16x32_bf16(wf[hl][g][kt], bh, acc[hl][g], 0, 0, 0);
        }

        // gates (i,f,g,o), new c & h; h' cols hc = 32w+16hl+q*4+r for node lid
#pragma unroll
        for (int hl = 0; hl < 2; hl++) {
            short4v hv;
#pragma unroll
            for (int r = 0; r < 4; r++) {
                float i_ = sigm(acc[hl][0][r]);
                float f_ = sigm(acc[hl][1][r]);
                float g_ = tanh_(acc[hl][2][r]);
                float o_ = sigm(acc[hl][3][r]);
                float cn = f_ * c[hl][r] + i_ * g_;
                c[hl][r] = cn;
                hv[r] = f2bfs(o_ * tanh_(cn));
            }
            if (t < 15) {
                *(short4v*)&hb[nxt][lid][32 * w + 16 * hl + 4 * q] = hv;
            } else {
                *(short4v*)(aggr + (size_t)(nodebase + lid) * 128 + 32 * w + 16 * hl + 4 * q) = hv;
            }
        }
        __syncthreads();
    }
}

extern "C" void kernel_launch(void* const* d_in, const int* in_sizes, int n_in,
                              void* d_out, int out_size, void* d_ws, size_t ws_size,
                              hipStream_t stream)
{
    const int N = 50000;
    const int* es = (const int*)d_in[1];
    char* ws = (char*)d_ws;

    // converted bf16 copies of the 19 used float tensors @[0,15MB)
    static const int idxs[19] = {0, 8,9,10,11,12,13,14,15,16, 17,18,19,20,21,22,23,24,25};
    bf16* conv[19];
    size_t off = 0;
    CvtAll ca;
    for (int k = 0; k < 19; k++) {
        conv[k] = (bf16*)ws + off;
        ca.t[k].src = d_in[idxs[k]];
        ca.t[k].dst = conv[k];
        ca.t[k].n = in_sizes[idxs[k]];
        off += (size_t)((in_sizes[idxs[k]] + 63) & ~63);
    }
    int* flag = (int*)(ws + ((size_t)15 << 20));
    bf16* xp   = (bf16*)(ws + ((size_t)16 << 20));   // [N,128], reused as aggr
    bf16* Y    = (bf16*)(ws + ((size_t)30 << 20));   // [N,512]
    bf16* h1   = (bf16*)(ws + ((size_t)84 << 20));   // [N,128]
    bf16* aggr = xp;

    const bf16 *xc  = conv[0];
    const bf16 *Wp1 = conv[1],  *bp1 = conv[2],  *Wih1 = conv[3],  *Whh1 = conv[4];
    const bf16 *bih1 = conv[5], *bhh1 = conv[6], *Wl1 = conv[7],   *bl1 = conv[8],  *Wr1 = conv[9];
    const bf16 *Wp2 = conv[10], *bp2 = conv[11], *Wih2 = conv[12], *Whh2 = conv[13];
    const bf16 *bih2 = conv[14], *bhh2 = conv[15], *Wl2 = conv[16], *bl2 = conv[17], *Wr2 = conv[18];

    dim3 blk(256);
    const int gx = (N + 63) / 64;    // 782
    const int gl = N / 16;           // 3125 (exact)

    detect_dtype<<<dim3(1), dim3(64), 0, stream>>>((const unsigned short*)d_in[0], flag);
    convert_inputs<<<dim3(1024), blk, 0, stream>>>(ca, flag);

    // ---- layer 1 ----
    gemm_bias<8, true, false, false, false><<<dim3(gx, 1), blk, 0, stream>>>(
        xc, Wp1, bp1, nullptr, nullptr, nullptr, xp, nullptr, N, 128, 128);
    gemm_bias<8, false, true, false, false><<<dim3(gx, 4), blk, 0, stream>>>(
        xp, Wih1, bih1, bhh1, nullptr, nullptr, Y, nullptr, N, 512, 512);
    lstm_aggr<<<dim3(gl), blk, 0, stream>>>(Y, es, Whh1, aggr, N);
    gemm_bias<8, true, false, true, false><<<dim3(gx, 1), blk, 0, stream>>>(
        aggr, Wl1, bl1, nullptr, xc, Wr1, h1, nullptr, N, 128, 128);

    // ---- layer 2 ----
    gemm_bias<8, true, false, false, false><<<dim3(gx, 1), blk, 0, stream>>>(
        h1, Wp2, bp2, nullptr, nullptr, nullptr, xp, nullptr, N, 128, 128);
    gemm_bias<8, false, true, false, false><<<dim3(gx, 4), blk, 0, stream>>>(
        xp, Wih2, bih2, bhh2, nullptr, nullptr, Y, nullptr, N, 512, 512);
    lstm_aggr<<<dim3(gl), blk, 0, stream>>>(Y, es, Whh2, aggr, N);
    gemm_bias<3, false, false, true, true><<<dim3(gx, 1), blk, 0, stream>>>(
        aggr, Wl2, bl2, nullptr, h1, Wr2, d_out, flag, N, 40, 40);
}